// Round 6
// baseline (627.709 us; speedup 1.0000x reference)
//
#include <hip/hip_runtime.h>
#include <hip/hip_bf16.h>

#define N_NODES 50000
#define N_EDGES 600000
#define D_IN    128
#define D_HID   1024
#define D_OUT   128

// ---------------------------------------------------------------------------
// Workspace layout (bytes):
//   hbf    : [N_NODES*128] bf16   @ 0            (12,800,000)
//   pairs  : [N_EDGES] int2       @ 12,800,000   ( 4,800,000)  {eid, src}
//   off    : [N_NODES+1] int      @ 17,600,000   (   200,016)
//   cursor : [N_NODES] int        @ 17,800,016   (   200,000)
//   deg    : [N_NODES] int        @ 18,000,016   (   200,000)
//   bsum   : [256] int            @ 18,200,016   (     1,024)
//   W1T    : [1024*128] bf16      @ 18,201,040   (   262,144)   [n][k]
//   W2T    : [128*1024] bf16      @ 18,463,184   (   262,144)   [n][k]
// ---------------------------------------------------------------------------
#define WS_H      0
#define WS_PAIRS  12800000
#define WS_OFF    17600000
#define WS_CURSOR 17800016
#define WS_DEG    18000016
#define WS_BSUM   18200016
#define WS_W1T    18201040
#define WS_W2T    18463184

typedef short bf16x8 __attribute__((ext_vector_type(8)));
typedef short s16x4  __attribute__((ext_vector_type(4)));
typedef float f32x4  __attribute__((ext_vector_type(4)));
typedef int   i32x2  __attribute__((ext_vector_type(2)));

// ---------------------------------------------------------------------------
// CSR step 1 + weight transpose, merged. Blocks [0, HIST_NB): histogram of
// dst. Blocks [HIST_NB, HIST_NB+256): transpose+cvt both weight matrices
// (independent work riding along -> one fewer launch).
// ---------------------------------------------------------------------------
#define HIST_NB 2344   // ceil(600000/256)

__global__ __launch_bounds__(256) void hist_tr_kernel(
    const int* __restrict__ dst, int* __restrict__ deg,
    const float* __restrict__ W1, __hip_bfloat16* __restrict__ w1t,
    const float* __restrict__ W2, __hip_bfloat16* __restrict__ w2t)
{
    __shared__ float tile[32][33];
    if (blockIdx.x < HIST_NB) {
        int e = blockIdx.x * blockDim.x + threadIdx.x;
        if (e < N_EDGES) atomicAdd(&deg[dst[e]], 1);
        return;
    }
    int b = blockIdx.x - HIST_NB;    // 0..255
    const float* in;
    __hip_bfloat16* outp;
    int rows, cols, c0, r0;
    if (b < 128) {
        in = W1; outp = w1t; rows = D_IN; cols = D_HID;
        c0 = (b & 31) * 32; r0 = (b >> 5) * 32;          // grid (32,4)
    } else {
        int bb = b - 128;
        in = W2; outp = w2t; rows = D_HID; cols = D_OUT;
        c0 = (bb & 3) * 32; r0 = (bb >> 2) * 32;         // grid (4,32)
    }
    int tx = threadIdx.x & 31, ty = threadIdx.x >> 5;    // ty 0..7
    #pragma unroll
    for (int i = 0; i < 32; i += 8)
        tile[ty + i][tx] = in[(size_t)(r0 + ty + i) * cols + (c0 + tx)];
    __syncthreads();
    #pragma unroll
    for (int i = 0; i < 32; i += 8)
        outp[(size_t)(c0 + ty + i) * rows + (r0 + tx)] =
            __float2bfloat16(tile[tx][ty + i]);
}

// ---------------------------------------------------------------------------
// CSR step 2a: per-block sums of deg (coalesced). 196 blocks x 256.
// ---------------------------------------------------------------------------
__global__ __launch_bounds__(256) void scan1_kernel(
    const int* __restrict__ deg, int* __restrict__ bsum)
{
    __shared__ int red[256];
    int t = threadIdx.x;
    int idx = blockIdx.x * 256 + t;
    red[t] = (idx < N_NODES) ? deg[idx] : 0;
    __syncthreads();
    for (int s = 128; s > 0; s >>= 1) {
        if (t < s) red[t] += red[t + s];
        __syncthreads();
    }
    if (t == 0) bsum[blockIdx.x] = red[0];
}

// ---------------------------------------------------------------------------
// CSR step 2b: exclusive scan of 196 block sums (single small block).
// Also writes off[N_NODES] = total.
// ---------------------------------------------------------------------------
#define SCAN_NB 196
__global__ __launch_bounds__(256) void scan2_kernel(
    int* __restrict__ bsum, int* __restrict__ off)
{
    __shared__ int sh[256];
    int t = threadIdx.x;
    int v = (t < SCAN_NB) ? bsum[t] : 0;
    sh[t] = v;
    __syncthreads();
    for (int ofs = 1; ofs < 256; ofs <<= 1) {
        int u = (t >= ofs) ? sh[t - ofs] : 0;
        __syncthreads();
        sh[t] += u;
        __syncthreads();
    }
    if (t < SCAN_NB) bsum[t] = sh[t] - v;       // exclusive
    if (t == 255) off[N_NODES] = sh[255];       // total == N_EDGES
}

// ---------------------------------------------------------------------------
// CSR step 2c: block-local scan + block offset -> off[], cursor[]
// ---------------------------------------------------------------------------
__global__ __launch_bounds__(256) void scan3_kernel(
    const int* __restrict__ deg, const int* __restrict__ bsum,
    int* __restrict__ off, int* __restrict__ cursor)
{
    __shared__ int sh[256];
    int t = threadIdx.x;
    int idx = blockIdx.x * 256 + t;
    int v = (idx < N_NODES) ? deg[idx] : 0;
    sh[t] = v;
    __syncthreads();
    for (int ofs = 1; ofs < 256; ofs <<= 1) {
        int u = (t >= ofs) ? sh[t - ofs] : 0;
        __syncthreads();
        sh[t] += u;
        __syncthreads();
    }
    if (idx < N_NODES) {
        int ex = bsum[blockIdx.x] + sh[t] - v;
        off[idx] = ex;
        cursor[idx] = ex;
    }
}

// ---------------------------------------------------------------------------
// CSR step 3: drop {eid, src} pairs into dst buckets.
// ---------------------------------------------------------------------------
__global__ __launch_bounds__(256) void fill_kernel(
    const int* __restrict__ dst, const int* __restrict__ src,
    int* __restrict__ cursor, int* __restrict__ pairs)
{
    int e = blockIdx.x * blockDim.x + threadIdx.x;
    if (e < N_EDGES) {
        int s = src[e];                       // coalesced
        int pos = atomicAdd(&cursor[dst[e]], 1);
        i32x2 v; v.x = e; v.y = s;
        *(i32x2*)(pairs + 2 * (size_t)pos) = v;   // 8B scatter
    }
}

// ---------------------------------------------------------------------------
// STANDALONE gather: one wave per node, BW-bound (proven structure-
// insensitive in rounds 0 vs 4). Wave-uniform {eid,src} pair loads,
// full-wave float2/lane row loads (512B coalesced per edge), 8-edge unroll.
// ---------------------------------------------------------------------------
__global__ __launch_bounds__(256) void gather_kernel(
    const float* __restrict__ feat,
    const float* __restrict__ edge_feat,
    const int*   __restrict__ pairs,          // [E] {eid, src}
    const int*   __restrict__ off,
    __hip_bfloat16* __restrict__ hbf)
{
    const int wv   = threadIdx.x >> 6;
    const int lane = threadIdx.x & 63;
    const int n = blockIdx.x * 4 + wv;
    if (n >= N_NODES) return;

    int i   = __builtin_amdgcn_readfirstlane(off[n]);
    int end = __builtin_amdgcn_readfirstlane(off[n + 1]);

    float2 a0 = make_float2(0.f, 0.f), a1 = a0, a2 = a0, a3 = a0;

    for (; i + 8 <= end; i += 8) {
        i32x2 p0 = *(const i32x2*)(pairs + 2 * (size_t)(i + 0));
        i32x2 p1 = *(const i32x2*)(pairs + 2 * (size_t)(i + 1));
        i32x2 p2 = *(const i32x2*)(pairs + 2 * (size_t)(i + 2));
        i32x2 p3 = *(const i32x2*)(pairs + 2 * (size_t)(i + 3));
        i32x2 p4 = *(const i32x2*)(pairs + 2 * (size_t)(i + 4));
        i32x2 p5 = *(const i32x2*)(pairs + 2 * (size_t)(i + 5));
        i32x2 p6 = *(const i32x2*)(pairs + 2 * (size_t)(i + 6));
        i32x2 p7 = *(const i32x2*)(pairs + 2 * (size_t)(i + 7));
        float2 e0 = ((const float2*)(edge_feat + (size_t)p0.x * D_IN))[lane];
        float2 g0 = ((const float2*)(feat      + (size_t)p0.y * D_IN))[lane];
        float2 e1 = ((const float2*)(edge_feat + (size_t)p1.x * D_IN))[lane];
        float2 g1 = ((const float2*)(feat      + (size_t)p1.y * D_IN))[lane];
        float2 e2 = ((const float2*)(edge_feat + (size_t)p2.x * D_IN))[lane];
        float2 g2 = ((const float2*)(feat      + (size_t)p2.y * D_IN))[lane];
        float2 e3 = ((const float2*)(edge_feat + (size_t)p3.x * D_IN))[lane];
        float2 g3 = ((const float2*)(feat      + (size_t)p3.y * D_IN))[lane];
        float2 e4 = ((const float2*)(edge_feat + (size_t)p4.x * D_IN))[lane];
        float2 g4 = ((const float2*)(feat      + (size_t)p4.y * D_IN))[lane];
        float2 e5 = ((const float2*)(edge_feat + (size_t)p5.x * D_IN))[lane];
        float2 g5 = ((const float2*)(feat      + (size_t)p5.y * D_IN))[lane];
        float2 e6 = ((const float2*)(edge_feat + (size_t)p6.x * D_IN))[lane];
        float2 g6 = ((const float2*)(feat      + (size_t)p6.y * D_IN))[lane];
        float2 e7 = ((const float2*)(edge_feat + (size_t)p7.x * D_IN))[lane];
        float2 g7 = ((const float2*)(feat      + (size_t)p7.y * D_IN))[lane];
        a0.x += e0.x + g0.x;  a0.y += e0.y + g0.y;
        a1.x += e1.x + g1.x;  a1.y += e1.y + g1.y;
        a2.x += e2.x + g2.x;  a2.y += e2.y + g2.y;
        a3.x += e3.x + g3.x;  a3.y += e3.y + g3.y;
        a0.x += e4.x + g4.x;  a0.y += e4.y + g4.y;
        a1.x += e5.x + g5.x;  a1.y += e5.y + g5.y;
        a2.x += e6.x + g6.x;  a2.y += e6.y + g6.y;
        a3.x += e7.x + g7.x;  a3.y += e7.y + g7.y;
    }
    for (; i + 2 <= end; i += 2) {
        i32x2 p0 = *(const i32x2*)(pairs + 2 * (size_t)(i + 0));
        i32x2 p1 = *(const i32x2*)(pairs + 2 * (size_t)(i + 1));
        float2 e0 = ((const float2*)(edge_feat + (size_t)p0.x * D_IN))[lane];
        float2 g0 = ((const float2*)(feat      + (size_t)p0.y * D_IN))[lane];
        float2 e1 = ((const float2*)(edge_feat + (size_t)p1.x * D_IN))[lane];
        float2 g1 = ((const float2*)(feat      + (size_t)p1.y * D_IN))[lane];
        a0.x += e0.x + g0.x;  a0.y += e0.y + g0.y;
        a1.x += e1.x + g1.x;  a1.y += e1.y + g1.y;
    }
    if (i < end) {
        i32x2 p = *(const i32x2*)(pairs + 2 * (size_t)i);
        float2 e = ((const float2*)(edge_feat + (size_t)p.x * D_IN))[lane];
        float2 g = ((const float2*)(feat      + (size_t)p.y * D_IN))[lane];
        a0.x += e.x + g.x;  a0.y += e.y + g.y;
    }
    float sx = (a0.x + a1.x) + (a2.x + a3.x);
    float sy = (a0.y + a1.y) + (a2.y + a3.y);
    __hip_bfloat162 hv;
    hv.x = __float2bfloat16(sx);
    hv.y = __float2bfloat16(sy);
    ((__hip_bfloat162*)(hbf + (size_t)n * D_IN))[lane] = hv;
}

// ---------------------------------------------------------------------------
// MFMA MLP, operand-swapped layer 1, 48-node tiles for occupancy.
// grid 1042 (4.07 blocks/CU), __launch_bounds__(256,4) caps VGPR at 128 ->
// 16 waves/CU (vs ~12 grid-limited at 64-node tiles). LDS 26.1KB.
//
// Layer1 (SWAPPED): D = W1T-frag (A) x h-frag (B); lane holds
//   H1[node = nt*16+lid][hid0 + half*4 + r] -> packed s16x4 LDS writes,
//   vector float4 bias. h-frags straight from L2-resident hbf.
//   wave wv owns hidden [jb + wv*32, +32) of each 128-col chunk.
// Layer2: A = q_s fragment, B = W2T rows; two K=64 halves; q_s
//   double-buffered -> ONE __syncthreads() per 128-col chunk (8 total).
// ---------------------------------------------------------------------------
#define QS_STRIDE 136   // shorts per q_s row (272 B = 17*16, banks shift 4/row)
#define MT_TILES  3     // 48 nodes per block

__global__ __launch_bounds__(256, 4) void mlp_mfma_kernel(
    const __hip_bfloat16* __restrict__ hbf,   // [N][128]
    const __hip_bfloat16* __restrict__ w1t,   // [1024][128]
    const float* __restrict__ b1,             // [1024]
    const __hip_bfloat16* __restrict__ w2t,   // [128][1024]
    const float* __restrict__ b2,             // [128]
    float* __restrict__ out)                  // [N][128]
{
    __shared__ __align__(16) short q_s[2][48 * QS_STRIDE];   // 26.1 KB

    const int t    = threadIdx.x;
    const int wv   = t >> 6;
    const int lane = t & 63;
    const int half = lane >> 4;    // quad 0..3
    const int lid  = lane & 15;
    const int nb   = blockIdx.x * 48;

    const short* hs  = (const short*)hbf;
    const short* w1s = (const short*)w1t;
    const short* w2s = (const short*)w2t;

    // ---- h fragments (B-operand for swapped layer1), straight from L2 ----
    bf16x8 hfrag[MT_TILES][4];
    #pragma unroll
    for (int nt = 0; nt < MT_TILES; ++nt) {
        int row = nb + nt * 16 + lid;
        if (row >= N_NODES) row = N_NODES - 1;   // clamp: dup valid row, no NaN
        #pragma unroll
        for (int ks = 0; ks < 4; ++ks)
            hfrag[nt][ks] = *(const bf16x8*)&hs[(size_t)row * 128 + ks * 32 + half * 8];
    }

    f32x4 acc[MT_TILES][2];
    #pragma unroll
    for (int mt = 0; mt < MT_TILES; ++mt) {
        acc[mt][0] = f32x4{0.f, 0.f, 0.f, 0.f};
        acc[mt][1] = f32x4{0.f, 0.f, 0.f, 0.f};
    }

    int pb = 0;
    for (int jb = 0; jb < D_HID; jb += 128, pb ^= 1) {
        // ---- layer 1 (swapped): wave wv computes hidden [jb+wv*32, +32) ----
        #pragma unroll
        for (int ht = 0; ht < 2; ++ht) {
            const int hid0 = jb + wv * 32 + ht * 16;
            bf16x8 w1f[4];
            #pragma unroll
            for (int ks = 0; ks < 4; ++ks)
                w1f[ks] = *(const bf16x8*)&w1s[(size_t)(hid0 + lid) * 128 + ks * 32 + half * 8];
            f32x4 bias4 = *(const f32x4*)&b1[hid0 + half * 4];
            #pragma unroll
            for (int nt = 0; nt < MT_TILES; ++nt) {
                f32x4 c = bias4;
                #pragma unroll
                for (int ks = 0; ks < 4; ++ks)
                    c = __builtin_amdgcn_mfma_f32_16x16x32_bf16(w1f[ks], hfrag[nt][ks], c, 0, 0, 0);
                // c[r] = H1[node=nt*16+lid][hid0 + half*4 + r]
                s16x4 hv;
                #pragma unroll
                for (int r = 0; r < 4; ++r) {
                    float v = fmaxf(c[r], 0.f);
                    __hip_bfloat16 bv = __float2bfloat16(v);
                    hv[r] = *(short*)&bv;
                }
                *(s16x4*)&q_s[pb][(nt * 16 + lid) * QS_STRIDE + wv * 32 + ht * 16 + half * 4] = hv;
            }
        }
        __syncthreads();   // q_s[pb] complete; also orders next write to pb^1
                           // after the previous chunk's reads of pb^1.

        // ---- layer 2: two K=64 halves of this chunk ----
        #pragma unroll
        for (int kh = 0; kh < 2; ++kh) {
            bf16x8 a2f[MT_TILES][2];
            #pragma unroll
            for (int mt = 0; mt < MT_TILES; ++mt)
                #pragma unroll
                for (int ks = 0; ks < 2; ++ks)
                    a2f[mt][ks] = *(const bf16x8*)&q_s[pb][(mt * 16 + lid) * QS_STRIDE + kh * 64 + ks * 32 + half * 8];
            #pragma unroll
            for (int nt = 0; nt < 2; ++nt) {
                #pragma unroll
                for (int ks = 0; ks < 2; ++ks) {
                    bf16x8 b2f = *(const bf16x8*)&w2s[(size_t)(wv * 32 + nt * 16 + lid) * 1024 + jb + kh * 64 + ks * 32 + half * 8];
                    #pragma unroll
                    for (int mt = 0; mt < MT_TILES; ++mt)
                        acc[mt][nt] = __builtin_amdgcn_mfma_f32_16x16x32_bf16(a2f[mt][ks], b2f, acc[mt][nt], 0, 0, 0);
                }
            }
        }
    }

    // ---- epilogue ----
    #pragma unroll
    for (int nt = 0; nt < 2; ++nt) {
        int col = wv * 32 + nt * 16 + lid;
        float bv = b2[col];
        #pragma unroll
        for (int mt = 0; mt < MT_TILES; ++mt) {
            #pragma unroll
            for (int r = 0; r < 4; ++r) {
                int row = nb + mt * 16 + half * 4 + r;
                if (row < N_NODES)
                    out[(size_t)row * D_OUT + col] = acc[mt][nt][r] + bv;
            }
        }
    }
}

// ---------------------------------------------------------------------------
extern "C" void kernel_launch(void* const* d_in, const int* in_sizes, int n_in,
                              void* d_out, int out_size, void* d_ws, size_t ws_size,
                              hipStream_t stream) {
    const float* feat      = (const float*)d_in[0];
    const float* edge_feat = (const float*)d_in[1];
    const int*   src       = (const int*)d_in[2];
    const int*   dst       = (const int*)d_in[3];
    const float* W1        = (const float*)d_in[4];
    const float* b1        = (const float*)d_in[5];
    const float* W2        = (const float*)d_in[6];
    const float* b2        = (const float*)d_in[7];
    float* out = (float*)d_out;

    char* ws = (char*)d_ws;
    __hip_bfloat16* hbf = (__hip_bfloat16*)(ws + WS_H);
    int*   pairs  = (int*)(ws + WS_PAIRS);
    int*   off    = (int*)(ws + WS_OFF);
    int*   cursor = (int*)(ws + WS_CURSOR);
    int*   deg    = (int*)(ws + WS_DEG);
    int*   bsum   = (int*)(ws + WS_BSUM);
    __hip_bfloat16* w1t = (__hip_bfloat16*)(ws + WS_W1T);
    __hip_bfloat16* w2t = (__hip_bfloat16*)(ws + WS_W2T);

    hipMemsetAsync(deg, 0, (size_t)N_NODES * sizeof(int), stream);

    // CSR build (hist + weight transposes merged into one launch)
    hist_tr_kernel<<<HIST_NB + 256, 256, 0, stream>>>(dst, deg, W1, w1t, W2, w2t);
    scan1_kernel<<<SCAN_NB, 256, 0, stream>>>(deg, bsum);
    scan2_kernel<<<1, 256, 0, stream>>>(bsum, off);
    scan3_kernel<<<SCAN_NB, 256, 0, stream>>>(deg, bsum, off, cursor);
    fill_kernel<<<(N_EDGES + 255) / 256, 256, 0, stream>>>(dst, src, cursor, pairs);

    // standalone gather at full occupancy (one wave per node)
    gather_kernel<<<(N_NODES + 3) / 4, 256, 0, stream>>>(
        feat, edge_feat, pairs, off, hbf);

    // MFMA MLP (operand-swapped layer 1, 48-node tiles)
    mlp_mfma_kernel<<<(N_NODES + 47) / 48, 256, 0, stream>>>(
        hbf, w1t, b1, w2t, b2, out);
}